// Round 1
// baseline (2117.678 us; speedup 1.0000x reference)
//
#include <hip/hip_runtime.h>
#include <hip/hip_bf16.h>
#include <cstdint>
#include <cstddef>

// Problem dims
#define Sd 1024
#define Dd 512
#define Hd 8
#define Fd 2048
#define Bd 8
#define EPSf 1e-3f

typedef __bf16 bf16x8 __attribute__((ext_vector_type(8)));
typedef float f32x4 __attribute__((ext_vector_type(4)));

#define BM 128
#define BN 128
#define BK 32
#define LDK 40  // padded LDS row (bf16 elems): 80B rows keep ds_read_b128 ~conflict-free

enum { EPI_BF16 = 0, EPI_F32 = 1, EPI_BNPRELU = 2 };

// ---- staging helpers: global (f32 or bf16) -> LDS bf16 tile [rows][LDK] ----
template <int F32>
__device__ inline void stage_rows(const void* __restrict__ src, int ld, int r0, int kt,
                                  __hip_bfloat16 (*dst)[LDK], int tid) {
  if (F32) {
    const float* p = (const float*)src;
#pragma unroll
    for (int i = 0; i < 4; ++i) {
      int idx = tid + i * 256;      // 1024 float4 slots = 128 rows x 8 groups
      int row = idx >> 3;
      int kg = idx & 7;
      const float4 v = *reinterpret_cast<const float4*>(p + (size_t)(r0 + row) * ld + kt * BK + kg * 4);
      __hip_bfloat16* d = &dst[row][kg * 4];
      d[0] = __float2bfloat16(v.x); d[1] = __float2bfloat16(v.y);
      d[2] = __float2bfloat16(v.z); d[3] = __float2bfloat16(v.w);
    }
  } else {
    const __hip_bfloat16* p = (const __hip_bfloat16*)src;
#pragma unroll
    for (int i = 0; i < 2; ++i) {
      int idx = tid + i * 256;      // 512 bf16x8 slots = 128 rows x 4 groups
      int row = idx >> 2;
      int kg = idx & 3;
      bf16x8 v = *reinterpret_cast<const bf16x8*>(p + (size_t)(r0 + row) * ld + kt * BK + kg * 8);
      *reinterpret_cast<bf16x8*>(&dst[row][kg * 8]) = v;
    }
  }
}

// B stored [K,N] row-major -> LDS transposed [n][k]
template <int F32>
__device__ inline void stage_B_normal(const void* __restrict__ src, int ld, int n0, int kt,
                                      __hip_bfloat16 (*dst)[LDK], int tid) {
  if (F32) {
    const float* p = (const float*)src;
#pragma unroll
    for (int i = 0; i < 4; ++i) {
      int idx = tid + i * 256;      // 32 k-rows x 32 n-groups(of 4)
      int kr = idx >> 5;
      int ng = idx & 31;
      const float4 v = *reinterpret_cast<const float4*>(p + (size_t)(kt * BK + kr) * ld + n0 + ng * 4);
      dst[ng * 4 + 0][kr] = __float2bfloat16(v.x);
      dst[ng * 4 + 1][kr] = __float2bfloat16(v.y);
      dst[ng * 4 + 2][kr] = __float2bfloat16(v.z);
      dst[ng * 4 + 3][kr] = __float2bfloat16(v.w);
    }
  } else {
    const __hip_bfloat16* p = (const __hip_bfloat16*)src;
#pragma unroll
    for (int i = 0; i < 2; ++i) {
      int idx = tid + i * 256;      // 32 k-rows x 16 n-groups(of 8)
      int kr = idx >> 4;
      int ng = idx & 15;
      bf16x8 v = *reinterpret_cast<const bf16x8*>(p + (size_t)(kt * BK + kr) * ld + n0 + ng * 8);
      const __hip_bfloat16* e = (const __hip_bfloat16*)&v;
#pragma unroll
      for (int j = 0; j < 8; ++j) dst[ng * 8 + j][kr] = e[j];
    }
  }
}

// ---- generic GEMM: C[M,N] = epi(alpha * A@B(+bias)) ----
// A: [M,K] row-major (f32 or bf16). B: BTRANS? [N,K] : [K,N] (f32 or bf16).
// grid = (N/BN, M/BM, Z); per-z strides in elements.
template <int AF32, int BF32, int BTRANS, int EPI>
__global__ __launch_bounds__(256, 2) void gemm_kernel(
    const void* __restrict__ A_, int lda, size_t strideA,
    const void* __restrict__ B_, int ldb, size_t strideB,
    const float* __restrict__ bias, size_t strideBias,
    void* __restrict__ C_, int ldc, size_t strideC,
    int K, float alpha,
    const float* __restrict__ bn_g, const float* __restrict__ bn_b,
    const float* __restrict__ bn_m, const float* __restrict__ bn_v,
    const float* __restrict__ pa) {
  __shared__ __hip_bfloat16 As[BM][LDK];
  __shared__ __hip_bfloat16 Bs[BN][LDK];

  const int tid = threadIdx.x;
  const int z = blockIdx.z;
  const int m0 = blockIdx.y * BM;
  const int n0 = blockIdx.x * BN;

  const char* A = (const char*)A_ + (size_t)z * strideA * (AF32 ? 4 : 2);
  const char* B = (const char*)B_ + (size_t)z * strideB * (BF32 ? 4 : 2);
  const float* bi = bias ? bias + (size_t)z * strideBias : nullptr;
  char* C = (char*)C_ + (size_t)z * strideC * ((EPI == EPI_F32) ? 4 : 2);

  const int lane = tid & 63;
  const int wv = tid >> 6;
  const int wm = (wv >> 1) * 64;
  const int wn = (wv & 1) * 64;
  const int fr = lane & 15;   // A-row / B-col / C-col within fragment
  const int kg = lane >> 4;   // k-group

  f32x4 acc[4][4] = {};

  const int nk = K / BK;
  for (int kt = 0; kt < nk; ++kt) {
    stage_rows<AF32>(A, lda, m0, kt, As, tid);
    if (BTRANS) stage_rows<BF32>(B, ldb, n0, kt, Bs, tid);
    else        stage_B_normal<BF32>(B, ldb, n0, kt, Bs, tid);
    __syncthreads();

    bf16x8 af[4], bfr[4];
#pragma unroll
    for (int mi = 0; mi < 4; ++mi)
      af[mi] = *reinterpret_cast<const bf16x8*>(&As[wm + mi * 16 + fr][kg * 8]);
#pragma unroll
    for (int ni = 0; ni < 4; ++ni)
      bfr[ni] = *reinterpret_cast<const bf16x8*>(&Bs[wn + ni * 16 + fr][kg * 8]);
#pragma unroll
    for (int mi = 0; mi < 4; ++mi)
#pragma unroll
      for (int ni = 0; ni < 4; ++ni)
        acc[mi][ni] = __builtin_amdgcn_mfma_f32_16x16x32_bf16(af[mi], bfr[ni], acc[mi][ni], 0, 0, 0);
    __syncthreads();
  }

  // epilogue: C/D layout col=lane&15, row=(lane>>4)*4+j  [m89-verified]
#pragma unroll
  for (int ni = 0; ni < 4; ++ni) {
    const int col = n0 + wn + ni * 16 + fr;
    const float bval = bi ? bi[col] : 0.f;
    float scale = 0.f, shift = 0.f;
    if (EPI == EPI_BNPRELU) {
      scale = bn_g[col] * rsqrtf(bn_v[col] + EPSf);
      shift = bn_b[col] - bn_m[col] * scale;
    }
#pragma unroll
    for (int mi = 0; mi < 4; ++mi) {
      const int rbase = m0 + wm + mi * 16 + kg * 4;
#pragma unroll
      for (int j = 0; j < 4; ++j) {
        const int row = rbase + j;
        float v = acc[mi][ni][j] * alpha + bval;
        if (EPI == EPI_F32) {
          ((float*)C)[(size_t)row * ldc + col] = v;
        } else if (EPI == EPI_BF16) {
          ((__hip_bfloat16*)C)[(size_t)row * ldc + col] = __float2bfloat16(v);
        } else {
          v = v * scale + shift;
          const float a = pa[(size_t)(row & (Sd - 1)) * Fd + col];
          v = v > 0.f ? v : a * v;
          ((__hip_bfloat16*)C)[(size_t)row * ldc + col] = __float2bfloat16(v);
        }
      }
    }
  }
}

// ---- reductions ----
__device__ inline float wave_max(float v) {
#pragma unroll
  for (int o = 32; o > 0; o >>= 1) v = fmaxf(v, __shfl_xor(v, o));
  return v;
}
__device__ inline float wave_sum(float v) {
#pragma unroll
  for (int o = 32; o > 0; o >>= 1) v += __shfl_xor(v, o);
  return v;
}

// softmax over rows of scores[h][1024][1024] f32; writes bf16 probs IN-PLACE at
// each f32 row's base address (bf16 ld = 2048 elems). grid(1024, H), 256 thr.
__global__ __launch_bounds__(256) void softmax_kernel(float* __restrict__ sc) {
  const int tid = threadIdx.x;
  float* rowp = sc + ((size_t)blockIdx.y << 20) + ((size_t)blockIdx.x << 10);
  const float4 v = reinterpret_cast<const float4*>(rowp)[tid];
  __shared__ float red[8];
  float mx = fmaxf(fmaxf(v.x, v.y), fmaxf(v.z, v.w));
  mx = wave_max(mx);
  if ((tid & 63) == 0) red[tid >> 6] = mx;
  __syncthreads();
  mx = fmaxf(fmaxf(red[0], red[1]), fmaxf(red[2], red[3]));
  const float e0 = __expf(v.x - mx), e1 = __expf(v.y - mx);
  const float e2 = __expf(v.z - mx), e3 = __expf(v.w - mx);
  float s = wave_sum(e0 + e1 + e2 + e3);
  if ((tid & 63) == 0) red[4 + (tid >> 6)] = s;
  __syncthreads();
  const float inv = 1.f / (red[4] + red[5] + red[6] + red[7]);
  __hip_bfloat16* op = reinterpret_cast<__hip_bfloat16*>(rowp);
  op[4 * tid + 0] = __float2bfloat16(e0 * inv);
  op[4 * tid + 1] = __float2bfloat16(e1 * inv);
  op[4 * tid + 2] = __float2bfloat16(e2 * inv);
  op[4 * tid + 3] = __float2bfloat16(e3 * inv);
}

// out[row] = LN(Xa[row] + Xb[row]) * gamma + beta ; rows of 512. grid(8192), 256 thr.
__global__ __launch_bounds__(256) void add_ln_kernel(
    const float* __restrict__ Xa, const float* __restrict__ Xb,
    const float* __restrict__ gamma, const float* __restrict__ beta,
    float* __restrict__ out) {
  const int tid = threadIdx.x;
  const size_t base = (size_t)blockIdx.x * Dd;
  const float2 a = reinterpret_cast<const float2*>(Xa + base)[tid];
  const float2 b = reinterpret_cast<const float2*>(Xb + base)[tid];
  const float r0 = a.x + b.x, r1 = a.y + b.y;
  float s = wave_sum(r0 + r1);
  float q = wave_sum(r0 * r0 + r1 * r1);
  __shared__ float rs[4], rq[4];
  if ((tid & 63) == 0) { rs[tid >> 6] = s; rq[tid >> 6] = q; }
  __syncthreads();
  const float mean = (rs[0] + rs[1] + rs[2] + rs[3]) * (1.f / Dd);
  const float msq = (rq[0] + rq[1] + rq[2] + rq[3]) * (1.f / Dd);
  const float inv = rsqrtf(msq - mean * mean + EPSf);
  const int c = tid * 2;
  out[base + c] = (r0 - mean) * inv * gamma[c] + beta[c];
  out[base + c + 1] = (r1 - mean) * inv * gamma[c + 1] + beta[c + 1];
}

extern "C" void kernel_launch(void* const* d_in, const int* in_sizes, int n_in,
                              void* d_out, int out_size, void* d_ws, size_t ws_size,
                              hipStream_t stream) {
  const float* Q = (const float*)d_in[0];
  const float* K = (const float*)d_in[1];
  const float* V = (const float*)d_in[2];
  const float* WQ = (const float*)d_in[3];
  const float* bQ = (const float*)d_in[4];
  const float* WK = (const float*)d_in[5];
  const float* bK = (const float*)d_in[6];
  const float* WV = (const float*)d_in[7];
  const float* bV = (const float*)d_in[8];
  const float* Wo = (const float*)d_in[9];
  const float* bo = (const float*)d_in[10];
  const float* W0 = (const float*)d_in[11];
  const float* b0 = (const float*)d_in[12];
  const float* g0 = (const float*)d_in[13];
  const float* be0 = (const float*)d_in[14];
  const float* m0 = (const float*)d_in[15];
  const float* v0 = (const float*)d_in[16];
  const float* a0 = (const float*)d_in[17];
  const float* W1 = (const float*)d_in[18];
  const float* b1 = (const float*)d_in[19];
  const float* g1 = (const float*)d_in[20];
  const float* be1 = (const float*)d_in[21];
  const float* m1 = (const float*)d_in[22];
  const float* v1 = (const float*)d_in[23];
  const float* a1 = (const float*)d_in[24];
  const float* W2 = (const float*)d_in[25];
  const float* b2 = (const float*)d_in[26];
  const float* ln0g = (const float*)d_in[27];
  const float* ln0b = (const float*)d_in[28];
  const float* ln1g = (const float*)d_in[29];
  const float* ln1b = (const float*)d_in[30];

  // workspace map (peak 125,829,120 B):
  //  [0, 64M)      cat bf16 [8192][4096]    -> later h0 bf16 [8192][2048] @0, h1 @32M
  //  [64M, 72M)    qh bf16 [8][1024][512]   -> later x f32 [8192][512] spans [64M,80M)
  //  [72M, 80M)    kh bf16
  //  [80M, 88M)    vh bf16
  //  [88M, 120M)   scores f32 [8][1024][1024] (attn bf16 written in-place)
  //                -> later mha f32 / ff f32 @88M
  char* ws = (char*)d_ws;
  __hip_bfloat16* cat = (__hip_bfloat16*)ws;
  __hip_bfloat16* qh = (__hip_bfloat16*)(ws + 67108864);
  __hip_bfloat16* kh = (__hip_bfloat16*)(ws + 75497472);
  __hip_bfloat16* vh = (__hip_bfloat16*)(ws + 83886080);
  float* sc = (float*)(ws + 92274688);
  float* mha = (float*)(ws + 92274688);
  float* xbuf = (float*)(ws + 67108864);
  __hip_bfloat16* h0 = (__hip_bfloat16*)ws;
  __hip_bfloat16* h1 = (__hip_bfloat16*)(ws + 33554432);
  float* ff = (float*)(ws + 92274688);

  const size_t SD = (size_t)Sd * Dd;   // 524288
  const size_t DD = (size_t)Dd * Dd;   // 262144
  const float* np = nullptr;

  for (int b = 0; b < Bd; ++b) {
    const float* Qb = Q + (size_t)b * SD;
    const float* Kb = K + (size_t)b * SD;
    const float* Vb = V + (size_t)b * SD;
    // qh/kh/vh[h] = Xb @ W[h] + bias[h]   (M=1024,N=512,K=512), z = head
    gemm_kernel<1, 1, 0, EPI_BF16><<<dim3(Dd / BN, Sd / BM, Hd), 256, 0, stream>>>(
        Qb, Dd, 0, WQ, Dd, DD, bQ, Dd, qh, Dd, SD, Dd, 1.f, np, np, np, np, np);
    gemm_kernel<1, 1, 0, EPI_BF16><<<dim3(Dd / BN, Sd / BM, Hd), 256, 0, stream>>>(
        Kb, Dd, 0, WK, Dd, DD, bK, Dd, kh, Dd, SD, Dd, 1.f, np, np, np, np, np);
    gemm_kernel<1, 1, 0, EPI_BF16><<<dim3(Dd / BN, Sd / BM, Hd), 256, 0, stream>>>(
        Vb, Dd, 0, WV, Dd, DD, bV, Dd, vh, Dd, SD, Dd, 1.f, np, np, np, np, np);
    // scores[h] = (qh[h] @ kh[h]^T) / D   (M=N=1024, K=512), f32
    gemm_kernel<0, 0, 1, EPI_F32><<<dim3(Sd / BN, Sd / BM, Hd), 256, 0, stream>>>(
        qh, Dd, SD, kh, Dd, SD, np, 0, sc, Sd, (size_t)Sd * Sd, Dd, 1.f / (float)Dd,
        np, np, np, np, np);
    // softmax rows -> bf16 probs in place
    softmax_kernel<<<dim3(Sd, Hd), 256, 0, stream>>>(sc);
    // ctx[h] = probs[h] @ vh[h] -> cat[b, :, h*512:(h+1)*512]  (M=1024,N=512,K=1024)
    gemm_kernel<0, 0, 0, EPI_BF16><<<dim3(Dd / BN, Sd / BM, Hd), 256, 0, stream>>>(
        (const __hip_bfloat16*)sc, 2 * Sd, (size_t)2 * Sd * Sd,
        vh, Dd, SD, np, 0,
        cat + (size_t)b * Sd * Hd * Dd, Hd * Dd, (size_t)Dd,
        Sd, 1.f, np, np, np, np, np);
  }
  // mha = cat @ Wo + bo  (M=8192, N=512, K=4096)
  gemm_kernel<0, 1, 0, EPI_F32><<<dim3(Dd / BN, (Bd * Sd) / BM, 1), 256, 0, stream>>>(
      cat, Hd * Dd, 0, Wo, Dd, 0, bo, 0, mha, Dd, 0, Hd * Dd, 1.f, np, np, np, np, np);
  // x = LN(Q + mha)
  add_ln_kernel<<<Bd * Sd, 256, 0, stream>>>(Q, mha, ln0g, ln0b, xbuf);
  // h0 = PReLU(BN(x @ W0 + b0))  (M=8192,N=2048,K=512)
  gemm_kernel<1, 1, 0, EPI_BNPRELU><<<dim3(Fd / BN, (Bd * Sd) / BM, 1), 256, 0, stream>>>(
      xbuf, Dd, 0, W0, Fd, 0, b0, 0, h0, Fd, 0, Dd, 1.f, g0, be0, m0, v0, a0);
  // h1 = PReLU(BN(h0 @ W1 + b1))  (M=8192,N=2048,K=2048)
  gemm_kernel<0, 1, 0, EPI_BNPRELU><<<dim3(Fd / BN, (Bd * Sd) / BM, 1), 256, 0, stream>>>(
      h0, Fd, 0, W1, Fd, 0, b1, 0, h1, Fd, 0, Fd, 1.f, g1, be1, m1, v1, a1);
  // ff = h1 @ W2 + b2  (M=8192,N=512,K=2048)
  gemm_kernel<0, 1, 0, EPI_F32><<<dim3(Dd / BN, (Bd * Sd) / BM, 1), 256, 0, stream>>>(
      h1, Fd, 0, W2, Dd, 0, b2, 0, ff, Dd, 0, Fd, 1.f, np, np, np, np, np);
  // out = LN(x + ff)
  add_ln_kernel<<<Bd * Sd, 256, 0, stream>>>(xbuf, ff, ln1g, ln1b, (float*)d_out);
}

// Round 2
// 1026.486 us; speedup vs baseline: 2.0630x; 2.0630x over previous
//
#include <hip/hip_runtime.h>
#include <hip/hip_bf16.h>
#include <cstdint>
#include <cstddef>

#define Sd 1024
#define Dd 512
#define Hd 8
#define Fd 2048
#define Bd 8
#define EPSf 1e-3f

typedef __bf16 bf16x8 __attribute__((ext_vector_type(8)));
typedef float f32x4 __attribute__((ext_vector_type(4)));
typedef __attribute__((address_space(3))) unsigned int lds_u32;
typedef __attribute__((address_space(1))) const unsigned int gl_u32;

#define BM 128
#define BN 128
#define BK 32

enum { EPI_BF16 = 0, EPI_F32 = 1, EPI_BNPRELU = 2 };

__device__ __forceinline__ void gl_lds16(const void* g, void* l) {
  __builtin_amdgcn_global_load_lds((gl_u32*)g, (lds_u32*)l, 16, 0, 0);
}

// ---- m97-structure BT-GEMM: C[M,N] = epi(alpha * A @ Bt^T + bias) ----
// A [M,K] bf16 row-major, Bt [N,K] bf16 row-major. Two-level z offsets:
// z1 = z>>zshift, z2 = z & mask; off = z1*s1 + z2*s2 (elements).
template <int EPI, int BIASROW>
__global__ __launch_bounds__(256, 2) void bt_gemm(
    const __hip_bfloat16* __restrict__ A_, int lda, size_t sA1, size_t sA2,
    const __hip_bfloat16* __restrict__ B_, int ldb, size_t sB1, size_t sB2,
    const float* __restrict__ bias_, size_t sBi1, size_t sBi2,
    void* __restrict__ C_, int ldc, size_t sC1, size_t sC2,
    int K, float alpha, int zshift,
    const float* __restrict__ bn_g, const float* __restrict__ bn_b,
    const float* __restrict__ bn_m, const float* __restrict__ bn_v,
    const float* __restrict__ pa) {
  __shared__ __hip_bfloat16 As[BM * BK];
  __shared__ __hip_bfloat16 Bs[BN * BK];

  const int tid = threadIdx.x;
  const int z = blockIdx.z;
  const int z1 = z >> zshift;
  const int z2 = z & ((1 << zshift) - 1);
  const int m0 = blockIdx.y * BM;
  const int n0 = blockIdx.x * BN;

  const __hip_bfloat16* A = A_ + (size_t)z1 * sA1 + (size_t)z2 * sA2;
  const __hip_bfloat16* Bt = B_ + (size_t)z1 * sB1 + (size_t)z2 * sB2;
  const float* bi = bias_ ? bias_ + (size_t)z1 * sBi1 + (size_t)z2 * sBi2 : nullptr;

  const int lane = tid & 63;
  const int wv = tid >> 6;
  const int wm = (wv >> 1) * 64;
  const int wn = (wv & 1) * 64;
  const int fr = lane & 15;
  const int kg = lane >> 4;

  // staging geometry: slot s in [0,512): row = s>>2, 16B chunk = s&3.
  const int srow = tid >> 2, sch = tid & 3;
  const size_t ldab = (size_t)lda * 2, ldbb = (size_t)ldb * 2;
  const char* Ap = (const char*)A + (size_t)(m0 + srow) * ldab + sch * 16;
  const char* Ap2 = Ap + 64 * ldab;
  const char* Bp = (const char*)Bt + (size_t)(n0 + srow) * ldbb + sch * 16;
  const char* Bp2 = Bp + 64 * ldbb;
  char* lA = (char*)As + tid * 16;
  char* lB = (char*)Bs + tid * 16;

  f32x4 acc[4][4] = {};

  for (int kt = 0; kt < K; kt += BK) {
    const size_t kb = (size_t)kt * 2;
    gl_lds16(Ap + kb, lA);
    gl_lds16(Ap2 + kb, lA + 4096);
    gl_lds16(Bp + kb, lB);
    gl_lds16(Bp2 + kb, lB + 4096);
    __syncthreads();

    bf16x8 afr[4], bfr[4];
#pragma unroll
    for (int mi = 0; mi < 4; ++mi)
      afr[mi] = *reinterpret_cast<const bf16x8*>(As + (wm + mi * 16 + fr) * BK + kg * 8);
#pragma unroll
    for (int ni = 0; ni < 4; ++ni)
      bfr[ni] = *reinterpret_cast<const bf16x8*>(Bs + (wn + ni * 16 + fr) * BK + kg * 8);
#pragma unroll
    for (int mi = 0; mi < 4; ++mi)
#pragma unroll
      for (int ni = 0; ni < 4; ++ni)
        acc[mi][ni] = __builtin_amdgcn_mfma_f32_16x16x32_bf16(afr[mi], bfr[ni], acc[mi][ni], 0, 0, 0);
    __syncthreads();
  }

  // epilogue: C/D layout col=lane&15, row=(lane>>4)*4+j  [m89-verified, passed R1]
  char* C = (char*)C_ + ((size_t)z1 * sC1 + (size_t)z2 * sC2) * ((EPI == EPI_F32) ? 4 : 2);
#pragma unroll
  for (int ni = 0; ni < 4; ++ni) {
    const int col = n0 + wn + ni * 16 + fr;
    float bcol = 0.f, scale = 0.f, shift = 0.f;
    if (bi && !BIASROW) bcol = bi[col];
    if (EPI == EPI_BNPRELU) {
      scale = bn_g[col] * rsqrtf(bn_v[col] + EPSf);
      shift = bn_b[col] - bn_m[col] * scale;
    }
#pragma unroll
    for (int mi = 0; mi < 4; ++mi) {
      const int rb = m0 + wm + mi * 16 + kg * 4;
#pragma unroll
      for (int j = 0; j < 4; ++j) {
        const int row = rb + j;
        float v = acc[mi][ni][j] * alpha + bcol;
        if (BIASROW) v += bi[row];
        if (EPI == EPI_F32) {
          ((float*)C)[(size_t)row * ldc + col] = v;
        } else if (EPI == EPI_BF16) {
          ((__hip_bfloat16*)C)[(size_t)row * ldc + col] = __float2bfloat16(v);
        } else {
          v = v * scale + shift;
          const float a = pa[(size_t)(row & (Sd - 1)) * Fd + col];
          v = v > 0.f ? v : a * v;
          ((__hip_bfloat16*)C)[(size_t)row * ldc + col] = __float2bfloat16(v);
        }
      }
    }
  }
}

// ---- transpose + convert: src [K][N] f32 -> dst [N][Kfull] bf16 ----
__global__ __launch_bounds__(256) void tconv(const float* __restrict__ src,
                                             __hip_bfloat16* __restrict__ dst,
                                             int N, int Kfull, size_t sIn, size_t sOut) {
  __shared__ __hip_bfloat16 t[64][65];
  const float* s = src + (size_t)blockIdx.z * sIn;
  __hip_bfloat16* d = dst + (size_t)blockIdx.z * sOut;
  const int k0 = blockIdx.y * 64, n0 = blockIdx.x * 64;
  const int tid = threadIdx.x;
#pragma unroll
  for (int i = 0; i < 4; ++i) {
    int slot = tid + i * 256;
    int r = slot >> 4, c = (slot & 15) * 4;
    const float4 v = *reinterpret_cast<const float4*>(s + (size_t)(k0 + r) * N + n0 + c);
    t[c + 0][r] = __float2bfloat16(v.x);
    t[c + 1][r] = __float2bfloat16(v.y);
    t[c + 2][r] = __float2bfloat16(v.z);
    t[c + 3][r] = __float2bfloat16(v.w);
  }
  __syncthreads();
#pragma unroll
  for (int i = 0; i < 2; ++i) {
    int slot = tid + i * 256;
    int n = slot >> 3, kc = (slot & 7) * 8;
    __hip_bfloat16 tmp[8];
#pragma unroll
    for (int j = 0; j < 8; ++j) tmp[j] = t[n][kc + j];
    *reinterpret_cast<float4*>(d + (size_t)(n0 + n) * Kfull + k0 + kc) =
        *reinterpret_cast<const float4*>(tmp);
  }
}

// ---- f32 -> bf16 elementwise, 3 tensors of 512K elems; grid(256,3) ----
__global__ __launch_bounds__(256) void conv3(const float* __restrict__ s0, const float* __restrict__ s1,
                                             const float* __restrict__ s2,
                                             __hip_bfloat16* __restrict__ d0, __hip_bfloat16* __restrict__ d1,
                                             __hip_bfloat16* __restrict__ d2) {
  const float* s = blockIdx.y == 0 ? s0 : (blockIdx.y == 1 ? s1 : s2);
  __hip_bfloat16* d = blockIdx.y == 0 ? d0 : (blockIdx.y == 1 ? d1 : d2);
  const int i = blockIdx.x * 256 + threadIdx.x;
  const float4 a = reinterpret_cast<const float4*>(s)[2 * i];
  const float4 b = reinterpret_cast<const float4*>(s)[2 * i + 1];
  __hip_bfloat16 tmp[8] = {
      __float2bfloat16(a.x), __float2bfloat16(a.y), __float2bfloat16(a.z), __float2bfloat16(a.w),
      __float2bfloat16(b.x), __float2bfloat16(b.y), __float2bfloat16(b.z), __float2bfloat16(b.w)};
  *reinterpret_cast<float4*>(d + 8 * (size_t)i) = *reinterpret_cast<const float4*>(tmp);
}

__global__ __launch_bounds__(256) void copy_bias2(const float* __restrict__ a,
                                                  const float* __restrict__ b,
                                                  float* __restrict__ d) {
  const int i = blockIdx.x * 256 + threadIdx.x;  // grid 16 -> 4096 each
  d[i] = a[i];
  d[4096 + i] = b[i];
}

// ---- reductions ----
__device__ inline float wave_max(float v) {
#pragma unroll
  for (int o = 32; o > 0; o >>= 1) v = fmaxf(v, __shfl_xor(v, o));
  return v;
}
__device__ inline float wave_sum(float v) {
#pragma unroll
  for (int o = 32; o > 0; o >>= 1) v += __shfl_xor(v, o);
  return v;
}

__device__ inline float b2f(unsigned short u) {
  unsigned x = ((unsigned)u) << 16; float f; __builtin_memcpy(&f, &x, 4); return f;
}
__device__ inline unsigned short f2b(float f) {
  __hip_bfloat16 h = __float2bfloat16(f); unsigned short u; __builtin_memcpy(&u, &h, 2); return u;
}

// softmax over rows of scores[h][1024][1024] bf16, in place. grid(1024, H), 256 thr.
__global__ __launch_bounds__(256) void softmax_bf16(__hip_bfloat16* __restrict__ sc) {
  const int tid = threadIdx.x;
  __hip_bfloat16* rowp = sc + ((size_t)blockIdx.y << 20) + ((size_t)blockIdx.x << 10);
  const ushort4 r = reinterpret_cast<const ushort4*>(rowp)[tid];
  const float v0 = b2f(r.x), v1 = b2f(r.y), v2 = b2f(r.z), v3 = b2f(r.w);
  __shared__ float red[8];
  float mx = fmaxf(fmaxf(v0, v1), fmaxf(v2, v3));
  mx = wave_max(mx);
  if ((tid & 63) == 0) red[tid >> 6] = mx;
  __syncthreads();
  mx = fmaxf(fmaxf(red[0], red[1]), fmaxf(red[2], red[3]));
  const float e0 = __expf(v0 - mx), e1 = __expf(v1 - mx);
  const float e2 = __expf(v2 - mx), e3 = __expf(v3 - mx);
  float s = wave_sum(e0 + e1 + e2 + e3);
  if ((tid & 63) == 0) red[4 + (tid >> 6)] = s;
  __syncthreads();
  const float inv = 1.f / (red[4] + red[5] + red[6] + red[7]);
  ushort4 o;
  o.x = f2b(e0 * inv); o.y = f2b(e1 * inv); o.z = f2b(e2 * inv); o.w = f2b(e3 * inv);
  reinterpret_cast<ushort4*>(rowp)[tid] = o;
}

// out = LN(Xa + Xb)*gamma + beta (rows of 512); optional bf16 copy. grid(8192), 256 thr.
__global__ __launch_bounds__(256) void add_ln(const float* __restrict__ Xa, const float* __restrict__ Xb,
                                              const float* __restrict__ gamma, const float* __restrict__ beta,
                                              float* __restrict__ out, __hip_bfloat16* __restrict__ outb) {
  const int tid = threadIdx.x;
  const size_t base = (size_t)blockIdx.x * Dd;
  const float2 a = reinterpret_cast<const float2*>(Xa + base)[tid];
  const float2 b = reinterpret_cast<const float2*>(Xb + base)[tid];
  const float r0 = a.x + b.x, r1 = a.y + b.y;
  float s = wave_sum(r0 + r1);
  float q = wave_sum(r0 * r0 + r1 * r1);
  __shared__ float rs[4], rq[4];
  if ((tid & 63) == 0) { rs[tid >> 6] = s; rq[tid >> 6] = q; }
  __syncthreads();
  const float mean = (rs[0] + rs[1] + rs[2] + rs[3]) * (1.f / Dd);
  const float msq = (rq[0] + rq[1] + rq[2] + rq[3]) * (1.f / Dd);
  const float inv = rsqrtf(msq - mean * mean + EPSf);
  const int c = tid * 2;
  const float y0 = (r0 - mean) * inv * gamma[c] + beta[c];
  const float y1 = (r1 - mean) * inv * gamma[c + 1] + beta[c + 1];
  out[base + c] = y0;
  out[base + c + 1] = y1;
  if (outb) {
    outb[base + c] = __float2bfloat16(y0);
    outb[base + c + 1] = __float2bfloat16(y1);
  }
}

extern "C" void kernel_launch(void* const* d_in, const int* in_sizes, int n_in,
                              void* d_out, int out_size, void* d_ws, size_t ws_size,
                              hipStream_t stream) {
  const float* Q = (const float*)d_in[0];
  const float* K = (const float*)d_in[1];
  const float* V = (const float*)d_in[2];
  const float* WQ = (const float*)d_in[3];
  const float* bQ = (const float*)d_in[4];
  const float* WK = (const float*)d_in[5];
  const float* bK = (const float*)d_in[6];
  const float* WV = (const float*)d_in[7];
  const float* bV = (const float*)d_in[8];
  const float* Wo = (const float*)d_in[9];
  const float* bo = (const float*)d_in[10];
  const float* W0 = (const float*)d_in[11];
  const float* b0 = (const float*)d_in[12];
  const float* g0 = (const float*)d_in[13];
  const float* be0 = (const float*)d_in[14];
  const float* m0 = (const float*)d_in[15];
  const float* v0 = (const float*)d_in[16];
  const float* a0 = (const float*)d_in[17];
  const float* W1 = (const float*)d_in[18];
  const float* b1 = (const float*)d_in[19];
  const float* g1 = (const float*)d_in[20];
  const float* be1 = (const float*)d_in[21];
  const float* m1 = (const float*)d_in[22];
  const float* v1 = (const float*)d_in[23];
  const float* a1 = (const float*)d_in[24];
  const float* W2 = (const float*)d_in[25];
  const float* b2 = (const float*)d_in[26];
  const float* ln0g = (const float*)d_in[27];
  const float* ln0b = (const float*)d_in[28];
  const float* ln1g = (const float*)d_in[29];
  const float* ln1b = (const float*)d_in[30];

  typedef __hip_bfloat16 bf;
  const size_t MB = 1u << 20;
  char* ws = (char*)d_ws;
  // -------- attention phase layout (peak 119 MiB + 32 KiB) --------
  bf* cat = (bf*)(ws);                   // [8192][4096]      0..64M
  bf* wqt = (bf*)(ws + 64 * MB);         // [8][512][512]     64..68M
  bf* wkt = (bf*)(ws + 68 * MB);         // 68..72M
  bf* wvt = (bf*)(ws + 72 * MB);         // 72..76M
  bf* qbf = (bf*)(ws + 76 * MB);         // [1024][512]       76..77M
  bf* kbf = (bf*)(ws + 77 * MB);         // 77..78M
  bf* vbf = (bf*)(ws + 78 * MB);         // 78..79M
  bf* qh = (bf*)(ws + 79 * MB);          // [8][1024][512]    79..87M
  bf* kh = (bf*)(ws + 87 * MB);          // 87..95M
  bf* vht = (bf*)(ws + 95 * MB);         // [8][512][1024]    95..103M
  bf* sc = (bf*)(ws + 103 * MB);         // [8][1024][1024]   103..119M
  float* bqk = (float*)(ws + 119 * MB);  // [2][8][512]
  // -------- post-attention layout (dead-buffer reuse, order matters) --------
  bf* wot = (bf*)(ws + 64 * MB);         // [512][4096]  (over WQt)
  float* mha = (float*)(ws + 68 * MB);   // [8192][512]  (over WKt..qh-head)
  float* xbuf = (float*)(ws + 84 * MB);  // [8192][512]
  bf* xb = (bf*)(ws + 100 * MB);         // [8192][512]
  bf* w0t = (bf*)(ws);                   // [2048][512]  (over cat, after Wo GEMM)
  bf* w1t = (bf*)(ws + 2 * MB);          // [2048][2048]
  bf* w2t = (bf*)(ws + 10 * MB);         // [512][2048]
  bf* h0 = (bf*)(ws + 12 * MB);          // [8192][2048]
  bf* h1 = (bf*)(ws + 44 * MB);          // [8192][2048]
  float* ff = (float*)(ws + 12 * MB);    // [8192][512]  (over h0, after FF1)

  const size_t SD = (size_t)Sd * Dd;     // 524288
  const size_t DD = (size_t)Dd * Dd;     // 262144
  const size_t SS = (size_t)Sd * Sd;     // 1048576
  const float* np = nullptr;

  // weights for attention
  tconv<<<dim3(8, 8, 8), 256, 0, stream>>>(WQ, wqt, Dd, Dd, DD, DD);
  tconv<<<dim3(8, 8, 8), 256, 0, stream>>>(WK, wkt, Dd, Dd, DD, DD);
  tconv<<<dim3(8, 8, 8), 256, 0, stream>>>(WV, wvt, Dd, Dd, DD, DD);
  copy_bias2<<<16, 256, 0, stream>>>(bQ, bK, bqk);

  for (int b = 0; b < Bd; ++b) {
    conv3<<<dim3(256, 3), 256, 0, stream>>>(Q + b * SD, K + b * SD, V + b * SD, qbf, kbf, vbf);
    // merged Q,K projection: z1 = 0:Q / 1:K, z2 = head. qh/kh[h] = Xbf @ Wt[h]^T + b
    bt_gemm<EPI_BF16, 0><<<dim3(4, 8, 16), 256, 0, stream>>>(
        qbf, Dd, SD, 0, wqt, Dd, 2 * DD * 4 / 2, DD, bqk, (size_t)Hd * Dd, Dd,
        qh, Dd, (size_t)8 * SD, SD, Dd, 1.f, 3, np, np, np, np, np);
    // vhT[h] = WVt[h] @ Vbf^T + bV[h] (row bias):  [512][1024]
    bt_gemm<EPI_BF16, 1><<<dim3(8, 4, 8), 256, 0, stream>>>(
        wvt, Dd, DD, 0, vbf, Dd, 0, 0, bV, Dd, 0,
        vht, Sd, SD, 0, Dd, 1.f, 0, np, np, np, np, np);
    // scores[h] = (qh[h] @ kh[h]^T) / D -> bf16
    bt_gemm<EPI_BF16, 0><<<dim3(8, 8, 8), 256, 0, stream>>>(
        qh, Dd, SD, 0, kh, Dd, SD, 0, np, 0, 0,
        sc, Sd, SS, 0, Dd, 1.f / (float)Dd, 0, np, np, np, np, np);
    softmax_bf16<<<dim3(Sd, Hd), 256, 0, stream>>>(sc);
    // ctx[h] = probs[h] @ vhT[h]^T -> cat[b,:,h*512:+512]
    bt_gemm<EPI_BF16, 0><<<dim3(4, 8, 8), 256, 0, stream>>>(
        sc, Sd, SS, 0, vht, Sd, SD, 0, np, 0, 0,
        cat + (size_t)b * Sd * Hd * Dd, Hd * Dd, Dd, 0, Sd, 1.f, 0, np, np, np, np, np);
  }

  // Wo
  tconv<<<dim3(8, 64, 1), 256, 0, stream>>>(Wo, wot, Dd, Hd * Dd, 0, 0);
  bt_gemm<EPI_F32, 0><<<dim3(4, 64, 1), 256, 0, stream>>>(
      cat, Hd * Dd, 0, 0, wot, Hd * Dd, 0, 0, bo, 0, 0,
      mha, Dd, 0, 0, Hd * Dd, 1.f, 0, np, np, np, np, np);
  add_ln<<<Bd * Sd, 256, 0, stream>>>(Q, mha, ln0g, ln0b, xbuf, xb);

  // FF weights (cat region is dead now)
  tconv<<<dim3(32, 8, 1), 256, 0, stream>>>(W0, w0t, Fd, Dd, 0, 0);
  tconv<<<dim3(32, 32, 1), 256, 0, stream>>>(W1, w1t, Fd, Fd, 0, 0);
  tconv<<<dim3(8, 32, 1), 256, 0, stream>>>(W2, w2t, Dd, Fd, 0, 0);

  bt_gemm<EPI_BNPRELU, 0><<<dim3(16, 64, 1), 256, 0, stream>>>(
      xb, Dd, 0, 0, w0t, Dd, 0, 0, b0, 0, 0,
      h0, Fd, 0, 0, Dd, 1.f, 0, g0, be0, m0, v0, a0);
  bt_gemm<EPI_BNPRELU, 0><<<dim3(16, 64, 1), 256, 0, stream>>>(
      h0, Fd, 0, 0, w1t, Fd, 0, 0, b1, 0, 0,
      h1, Fd, 0, 0, Fd, 1.f, 0, g1, be1, m1, v1, a1);
  bt_gemm<EPI_F32, 0><<<dim3(4, 64, 1), 256, 0, stream>>>(
      h1, Fd, 0, 0, w2t, Fd, 0, 0, b2, 0, 0,
      ff, Dd, 0, 0, Fd, 1.f, 0, np, np, np, np, np);
  add_ln<<<Bd * Sd, 256, 0, stream>>>(xbuf, ff, ln1g, ln1b, (float*)d_out, nullptr);
}